// Round 1
// baseline (587.379 us; speedup 1.0000x reference)
//
#include <hip/hip_runtime.h>

typedef __attribute__((ext_vector_type(8))) __bf16 bf16x8;
typedef __attribute__((ext_vector_type(4))) float floatx4;

static __device__ __forceinline__ floatx4 mfma16(bf16x8 a, bf16x8 b, floatx4 c) {
  return __builtin_amdgcn_mfma_f32_16x16x32_bf16(a, b, c, 0, 0, 0);
}

static __device__ __forceinline__ unsigned short f2b_bits(float f) {
  __bf16 h = (__bf16)f;
  return __builtin_bit_cast(unsigned short, h);
}

// ---------------------------------------------------------------- cast kernel
// x: 16777216 floats -> bf16 ; W: 1048576 floats -> bf16
__global__ void cast_kernel(const float4* __restrict__ x, const float4* __restrict__ w,
                            ushort4* __restrict__ xb, ushort4* __restrict__ wb) {
  int i = blockIdx.x * 256 + threadIdx.x;
  if (i < 4194304) {
    float4 v = x[i];
    ushort4 o;
    o.x = f2b_bits(v.x); o.y = f2b_bits(v.y); o.z = f2b_bits(v.z); o.w = f2b_bits(v.w);
    xb[i] = o;
  } else {
    int j = i - 4194304;
    if (j < 262144) {
      float4 v = w[j];
      ushort4 o;
      o.x = f2b_bits(v.x); o.y = f2b_bits(v.y); o.z = f2b_bits(v.z); o.w = f2b_bits(v.w);
      wb[j] = o;
    }
  }
}

// ---------------------------------------------------------------- z^T = (x @ W^T)^T
// A = xb [16384 x 1024] row-major bf16 (m = b*2048 + s)
// B = wb [1024 x 1024] row-major bf16 (rows = output dim n)  -> NT GEMM
// out: zT[b][n][s] bf16  (transposed store for flash V-fragment loads)
__global__ __launch_bounds__(256, 3) void gemm_zT(const unsigned short* __restrict__ xb,
                                                  const unsigned short* __restrict__ wb,
                                                  unsigned short* __restrict__ zT) {
  // fragment-contiguous LDS: [8 rowgroups][64 lanes] of 16B
  __shared__ bf16x8 a_lds[512];
  __shared__ bf16x8 b_lds[512];
  const int tid = threadIdx.x;
  const int wid = tid >> 6, lane = tid & 63;
  const int wr = wid >> 1, wc = wid & 1;
  const int lr = lane & 15, lq = lane >> 4;
  const int m0 = blockIdx.x * 128, n0 = blockIdx.y * 128;

  floatx4 acc[4][4] = {};

  // each wave stages A rowgroups {2*wid, 2*wid+1} and same for B
  const unsigned short* ga0 = xb + (m0 + wid * 32 + lr) * 1024 + lq * 8;
  const unsigned short* ga1 = ga0 + 16 * 1024;
  const unsigned short* gb0 = wb + (n0 + wid * 32 + lr) * 1024 + lq * 8;
  const unsigned short* gb1 = gb0 + 16 * 1024;
  bf16x8* la0 = &a_lds[(wid * 2 + 0) * 64 + lane];
  bf16x8* la1 = &a_lds[(wid * 2 + 1) * 64 + lane];
  bf16x8* lb0 = &b_lds[(wid * 2 + 0) * 64 + lane];
  bf16x8* lb1 = &b_lds[(wid * 2 + 1) * 64 + lane];

  for (int k0 = 0; k0 < 1024; k0 += 32) {
    *la0 = *(const bf16x8*)(ga0 + k0);
    *la1 = *(const bf16x8*)(ga1 + k0);
    *lb0 = *(const bf16x8*)(gb0 + k0);
    *lb1 = *(const bf16x8*)(gb1 + k0);
    __syncthreads();
    bf16x8 af[4], bfr[4];
#pragma unroll
    for (int i = 0; i < 4; ++i) af[i] = a_lds[(wr * 4 + i) * 64 + lane];
#pragma unroll
    for (int j = 0; j < 4; ++j) bfr[j] = b_lds[(wc * 4 + j) * 64 + lane];
#pragma unroll
    for (int i = 0; i < 4; ++i)
#pragma unroll
      for (int j = 0; j < 4; ++j)
        acc[i][j] = mfma16(af[i], bfr[j], acc[i][j]);
    __syncthreads();
  }

  // epilogue: C/D layout col = lane&15, row = lq*4 + v  ->  zT[b][n][s]
  const int bb = m0 >> 11;           // batch constant per block (m0 multiple of 128)
  const int sb = m0 & 2047;
#pragma unroll
  for (int i = 0; i < 4; ++i) {
    const int srow = sb + wr * 64 + i * 16 + lq * 4;
#pragma unroll
    for (int j = 0; j < 4; ++j) {
      const int n = n0 + wc * 64 + j * 16 + lr;
      unsigned short* dst = zT + ((bb << 10) | n) * 2048 + srow;
#pragma unroll
      for (int v = 0; v < 4; ++v) dst[v] = f2b_bits(acc[i][j][v]);
    }
  }
}

// ---------------------------------------------------------------- flash attention
// y[b, q, :] = softmax_causal(x_b x_b^T / 32) @ z_b
// Br=32, Bc=32, 4 waves, wave w owns D-slice [w*256, w*256+256)
__global__ __launch_bounds__(256, 2) void flash_attn(const unsigned short* __restrict__ xb,
                                                     const unsigned short* __restrict__ zT,
                                                     float* __restrict__ out) {
  __shared__ float red[4][32][36];  // padded: +4 floats/row breaks bank aliasing
  const int tid = threadIdx.x;
  const int wid = tid >> 6, lane = tid & 63;
  const int lr = lane & 15, lq = lane >> 4;
  const int i = blockIdx.x;
  int b, qt;
  if (i < 256) { b = i & 7; qt = 63 - (i >> 3); }   // long blocks first
  else { int j = i - 256; b = j & 7; qt = j >> 3; } // paired short blocks
  const int dw = wid * 256;

  const unsigned short* xbb = xb + b * (2048 * 1024);
  const unsigned short* zTb = zT + b * (1024 * 2048);

  // Q fragments in registers: A-layout row = lane&15, k = lq*8+j within 32-chunks
  bf16x8 qf[2][8];
#pragma unroll
  for (int rg = 0; rg < 2; ++rg)
#pragma unroll
    for (int kc = 0; kc < 8; ++kc)
      qf[rg][kc] = *(const bf16x8*)(xbb + (qt * 32 + rg * 16 + lr) * 1024 + dw + kc * 32 + lq * 8);

  floatx4 O[2][16] = {};
  float m_old[2] = {-3.0e38f, -3.0e38f};
  float l_run[2] = {0.0f, 0.0f};

  for (int kt = 0; kt <= qt; ++kt) {
    // ---- QK^T partial (this wave's 256-wide D-slice), K frags direct from global
    floatx4 S[2][2] = {};
    const unsigned short* kbase = xbb + (kt * 32 + lr) * 1024 + dw + lq * 8;
#pragma unroll
    for (int kc = 0; kc < 8; ++kc) {
      bf16x8 kf0 = *(const bf16x8*)(kbase + kc * 32);
      bf16x8 kf1 = *(const bf16x8*)(kbase + 16 * 1024 + kc * 32);
      S[0][0] = mfma16(qf[0][kc], kf0, S[0][0]);
      S[0][1] = mfma16(qf[0][kc], kf1, S[0][1]);
      S[1][0] = mfma16(qf[1][kc], kf0, S[1][0]);
      S[1][1] = mfma16(qf[1][kc], kf1, S[1][1]);
    }
    // ---- write partials for cross-wave reduction (C/D layout scatter)
#pragma unroll
    for (int rg = 0; rg < 2; ++rg)
#pragma unroll
      for (int ng = 0; ng < 2; ++ng)
#pragma unroll
        for (int v = 0; v < 4; ++v)
          red[wid][rg * 16 + lq * 4 + v][ng * 16 + lr] = S[rg][ng][v];
    __syncthreads();

    // ---- redundant per-wave online softmax (lane owns row lr of each rowgroup, cols lq*8..+7)
    float alpha[2];
    bf16x8 pf[2];
#pragma unroll
    for (int rg = 0; rg < 2; ++rg) {
      const int row = rg * 16 + lr;
      float s[8];
#pragma unroll
      for (int h = 0; h < 2; ++h) {
        float4 t0 = *(const float4*)&red[0][row][lq * 8 + h * 4];
        float4 t1 = *(const float4*)&red[1][row][lq * 8 + h * 4];
        float4 t2 = *(const float4*)&red[2][row][lq * 8 + h * 4];
        float4 t3 = *(const float4*)&red[3][row][lq * 8 + h * 4];
        s[h * 4 + 0] = t0.x + t1.x + t2.x + t3.x;
        s[h * 4 + 1] = t0.y + t1.y + t2.y + t3.y;
        s[h * 4 + 2] = t0.z + t1.z + t2.z + t3.z;
        s[h * 4 + 3] = t0.w + t1.w + t2.w + t3.w;
      }
      if (kt == qt) {  // diagonal tile: causal mask col > row
#pragma unroll
        for (int j2 = 0; j2 < 8; ++j2)
          if (lq * 8 + j2 > row) s[j2] = -3.0e38f;
      }
      float mt = s[0];
#pragma unroll
      for (int j2 = 1; j2 < 8; ++j2) mt = fmaxf(mt, s[j2]);
      mt = fmaxf(mt, __shfl_xor(mt, 16));
      mt = fmaxf(mt, __shfl_xor(mt, 32));
      const float mn = fmaxf(m_old[rg], mt);
      alpha[rg] = __expf((m_old[rg] - mn) * 0.03125f);  // logits scaled by 1/sqrt(1024) at exp
      m_old[rg] = mn;
      float p[8], ps = 0.0f;
#pragma unroll
      for (int j2 = 0; j2 < 8; ++j2) {
        p[j2] = __expf((s[j2] - mn) * 0.03125f);
        ps += p[j2];
      }
      ps += __shfl_xor(ps, 16);
      ps += __shfl_xor(ps, 32);
      l_run[rg] = l_run[rg] * alpha[rg] + ps;
      bf16x8 pk;
#pragma unroll
      for (int j2 = 0; j2 < 8; ++j2) pk[j2] = (__bf16)p[j2];
      pf[rg] = pk;  // already in A-operand layout: row = lane&15, k = lq*8+j
    }
    __syncthreads();  // protect red[] before next iteration's writes

    // ---- rescale O by alpha (alpha indexed by C-layout row lq*4+v, fetch via shuffle)
#pragma unroll
    for (int rg = 0; rg < 2; ++rg) {
      floatx4 av;
#pragma unroll
      for (int v = 0; v < 4; ++v) av[v] = __shfl(alpha[rg], lq * 4 + v);
#pragma unroll
      for (int ng = 0; ng < 16; ++ng) O[rg][ng] *= av;
    }

    // ---- PV: V frags direct from zT (one 64B line = one col's 32-key tile)
    const unsigned short* vbase = zTb + (dw + lr) * 2048 + kt * 32 + lq * 8;
#pragma unroll
    for (int ng = 0; ng < 16; ++ng) {
      bf16x8 vf = *(const bf16x8*)(vbase + ng * 16 * 2048);
      O[0][ng] = mfma16(pf[0], vf, O[0][ng]);
      O[1][ng] = mfma16(pf[1], vf, O[1][ng]);
    }
  }

  // ---- epilogue: divide by softmax denom, store fp32
  float* outb = out + b * (2048 * 1024);
#pragma unroll
  for (int rg = 0; rg < 2; ++rg) {
    float li[4];
#pragma unroll
    for (int v = 0; v < 4; ++v) li[v] = 1.0f / __shfl(l_run[rg], lq * 4 + v);
#pragma unroll
    for (int ng = 0; ng < 16; ++ng)
#pragma unroll
      for (int v = 0; v < 4; ++v)
        outb[(qt * 32 + rg * 16 + lq * 4 + v) * 1024 + dw + ng * 16 + lr] = O[rg][ng][v] * li[v];
  }
}

// ---------------------------------------------------------------- launcher
extern "C" void kernel_launch(void* const* d_in, const int* in_sizes, int n_in,
                              void* d_out, int out_size, void* d_ws, size_t ws_size,
                              hipStream_t stream) {
  const float* x = (const float*)d_in[0];  // [8][2048][1024]
  const float* W = (const float*)d_in[1];  // [1024][1024]
  float* out = (float*)d_out;              // [8][2048][1024]
  char* ws = (char*)d_ws;
  unsigned short* xb = (unsigned short*)ws;                              // 33554432 B bf16 x
  unsigned short* wb = (unsigned short*)(ws + (size_t)33554432);         //  2097152 B bf16 W
  unsigned short* zT = (unsigned short*)(ws + (size_t)35651584);         // 33554432 B bf16 z^T

  cast_kernel<<<17408, 256, 0, stream>>>((const float4*)x, (const float4*)W,
                                         (ushort4*)xb, (ushort4*)wb);
  gemm_zT<<<dim3(128, 8), 256, 0, stream>>>(xb, wb, zT);
  flash_attn<<<512, 256, 0, stream>>>(xb, zT, out);
}

// Round 2
// 355.609 us; speedup vs baseline: 1.6518x; 1.6518x over previous
//
#include <hip/hip_runtime.h>

typedef __attribute__((ext_vector_type(8))) __bf16 bf16x8;
typedef __attribute__((ext_vector_type(4))) float floatx4;

static __device__ __forceinline__ floatx4 mfma16(bf16x8 a, bf16x8 b, floatx4 c) {
  return __builtin_amdgcn_mfma_f32_16x16x32_bf16(a, b, c, 0, 0, 0);
}

static __device__ __forceinline__ unsigned short f2b_bits(float f) {
  __bf16 h = (__bf16)f;
  return __builtin_bit_cast(unsigned short, h);
}

// async global -> LDS, 16B per lane. LDS dest is wave-uniform base + lane*16.
static __device__ __forceinline__ void stage16(const void* g, void* l) {
  __builtin_amdgcn_global_load_lds(
      (__attribute__((address_space(1))) void*)(unsigned long long)g,
      (__attribute__((address_space(3))) void*)(unsigned int)(unsigned long long)l,
      16, 0, 0);
}

// ---------------------------------------------------------------- cast + zero lsum
__global__ void cast_kernel(const float4* __restrict__ x, const float4* __restrict__ w,
                            ushort4* __restrict__ xb, ushort4* __restrict__ wb,
                            float* __restrict__ lsum) {
  int i = blockIdx.x * 256 + threadIdx.x;
  if (i < 4194304) {
    float4 v = x[i];
    ushort4 o;
    o.x = f2b_bits(v.x); o.y = f2b_bits(v.y); o.z = f2b_bits(v.z); o.w = f2b_bits(v.w);
    xb[i] = o;
  } else if (i < 4456448) {
    int j = i - 4194304;
    float4 v = w[j];
    ushort4 o;
    o.x = f2b_bits(v.x); o.y = f2b_bits(v.y); o.z = f2b_bits(v.z); o.w = f2b_bits(v.w);
    wb[j] = o;
  } else {
    int j = i - 4456448;
    if (j < 16384) lsum[j] = 0.0f;
  }
}

// ---------------------------------------------------------------- z^T = (x @ W^T)^T
// A = xb [16384 x 1024] bf16 rowmajor, B = wb [1024 x 1024] bf16 rowmajor (NT)
// out zT[b][n][s] bf16 for PV's B-operand (16B contiguous along keys)
__global__ __launch_bounds__(256, 3) void gemm_zT(const unsigned short* __restrict__ xb,
                                                  const unsigned short* __restrict__ wb,
                                                  unsigned short* __restrict__ zT) {
  __shared__ bf16x8 a_lds[512];
  __shared__ bf16x8 b_lds[512];
  const int tid = threadIdx.x, wid = tid >> 6, lane = tid & 63;
  const int wr = wid >> 1, wc = wid & 1, lr = lane & 15, lq = lane >> 4;
  const int g = blockIdx.x;              // g = y*128 + x so same-x blocks share an XCD
  const int xt = g & 127, yt = g >> 7;
  const int m0 = xt * 128, n0 = yt * 128;

  floatx4 acc[4][4] = {};
  const unsigned short* ga0 = xb + (m0 + (2 * wid + 0) * 16 + lr) * 1024 + lq * 8;
  const unsigned short* ga1 = xb + (m0 + (2 * wid + 1) * 16 + lr) * 1024 + lq * 8;
  const unsigned short* gb0 = wb + (n0 + (2 * wid + 0) * 16 + lr) * 1024 + lq * 8;
  const unsigned short* gb1 = wb + (n0 + (2 * wid + 1) * 16 + lr) * 1024 + lq * 8;
  bf16x8* la0 = &a_lds[(2 * wid + 0) * 64];
  bf16x8* la1 = &a_lds[(2 * wid + 1) * 64];
  bf16x8* lb0 = &b_lds[(2 * wid + 0) * 64];
  bf16x8* lb1 = &b_lds[(2 * wid + 1) * 64];

  for (int k0 = 0; k0 < 1024; k0 += 32) {
    stage16(ga0 + k0, la0);
    stage16(ga1 + k0, la1);
    stage16(gb0 + k0, lb0);
    stage16(gb1 + k0, lb1);
    __syncthreads();
    bf16x8 af[4], bfr[4];
#pragma unroll
    for (int i = 0; i < 4; ++i) af[i] = a_lds[(wr * 4 + i) * 64 + lane];
#pragma unroll
    for (int j = 0; j < 4; ++j) bfr[j] = b_lds[(wc * 4 + j) * 64 + lane];
#pragma unroll
    for (int i = 0; i < 4; ++i)
#pragma unroll
      for (int j = 0; j < 4; ++j) acc[i][j] = mfma16(af[i], bfr[j], acc[i][j]);
    __syncthreads();
  }

  const int bb = m0 >> 11, sb = m0 & 2047;
#pragma unroll
  for (int i = 0; i < 4; ++i) {
    const int srow = sb + wr * 64 + i * 16 + lq * 4;
#pragma unroll
    for (int j = 0; j < 4; ++j) {
      const int n = n0 + wc * 64 + j * 16 + lr;
      ushort4 o;
      o.x = f2b_bits(acc[i][j][0]); o.y = f2b_bits(acc[i][j][1]);
      o.z = f2b_bits(acc[i][j][2]); o.w = f2b_bits(acc[i][j][3]);
      *(ushort4*)(zT + (((size_t)(bb << 10) | n) * 2048 + srow)) = o;
    }
  }
}

// ---------------------------------------------------------------- QK^T causal tiles + exp epilogue
// P_unnorm = exp(x_q . x_k / 32 - 44) bf16, packed lower-tri tiles [b][tri(mt)+nt][128][128]
// row sums accumulated into lsum[b*2048+q] via atomics
__global__ __launch_bounds__(256, 3) void qk_exp(const unsigned short* __restrict__ xb,
                                                 unsigned short* __restrict__ P,
                                                 float* __restrict__ lsum) {
  __shared__ bf16x8 a_lds[512];
  __shared__ bf16x8 b_lds[512];
  const int tid = threadIdx.x, wid = tid >> 6, lane = tid & 63;
  const int wr = wid >> 1, wc = wid & 1, lr = lane & 15, lq = lane >> 4;
  const int t = blockIdx.x, b = t & 7, idx = t >> 3;
  int mt = (int)((sqrtf(8.0f * idx + 1.0f) - 1.0f) * 0.5f);
  while ((mt + 1) * (mt + 2) / 2 <= idx) ++mt;
  while (mt * (mt + 1) / 2 > idx) --mt;
  const int nt = idx - mt * (mt + 1) / 2;
  const unsigned short* xbb = xb + (size_t)b * (2048 * 1024);
  const int q0 = mt * 128, k0t = nt * 128;

  floatx4 acc[4][4] = {};
  const unsigned short* ga0 = xbb + (q0 + (2 * wid + 0) * 16 + lr) * 1024 + lq * 8;
  const unsigned short* ga1 = xbb + (q0 + (2 * wid + 1) * 16 + lr) * 1024 + lq * 8;
  const unsigned short* gb0 = xbb + (k0t + (2 * wid + 0) * 16 + lr) * 1024 + lq * 8;
  const unsigned short* gb1 = xbb + (k0t + (2 * wid + 1) * 16 + lr) * 1024 + lq * 8;
  bf16x8* la0 = &a_lds[(2 * wid + 0) * 64];
  bf16x8* la1 = &a_lds[(2 * wid + 1) * 64];
  bf16x8* lb0 = &b_lds[(2 * wid + 0) * 64];
  bf16x8* lb1 = &b_lds[(2 * wid + 1) * 64];

  for (int k0 = 0; k0 < 1024; k0 += 32) {
    stage16(ga0 + k0, la0);
    stage16(ga1 + k0, la1);
    stage16(gb0 + k0, lb0);
    stage16(gb1 + k0, lb1);
    __syncthreads();
    bf16x8 af[4], bfr[4];
#pragma unroll
    for (int i = 0; i < 4; ++i) af[i] = a_lds[(wr * 4 + i) * 64 + lane];
#pragma unroll
    for (int j = 0; j < 4; ++j) bfr[j] = b_lds[(wc * 4 + j) * 64 + lane];
#pragma unroll
    for (int i = 0; i < 4; ++i)
#pragma unroll
      for (int j = 0; j < 4; ++j) acc[i][j] = mfma16(af[i], bfr[j], acc[i][j]);
    __syncthreads();
  }

  unsigned short* Pt = P + ((size_t)b * 136 + (size_t)(mt * (mt + 1) / 2 + nt)) * 16384;
  const bool diag = (mt == nt);
#pragma unroll
  for (int i = 0; i < 4; ++i) {
    const int row_l = wr * 64 + i * 16 + lq * 4;
    floatx4 rs = {0.0f, 0.0f, 0.0f, 0.0f};
#pragma unroll
    for (int j = 0; j < 4; ++j) {
      const int col_l = wc * 64 + j * 16 + lr;
#pragma unroll
      for (int v = 0; v < 4; ++v) {
        float p = __expf(acc[i][j][v] * 0.03125f - 44.0f);
        if (diag && col_l > row_l + v) p = 0.0f;
        Pt[(row_l + v) * 128 + col_l] = f2b_bits(p);
        rs[v] += p;
      }
    }
#pragma unroll
    for (int v = 0; v < 4; ++v) {
      float s = rs[v];
      s += __shfl_xor(s, 1);
      s += __shfl_xor(s, 2);
      s += __shfl_xor(s, 4);
      s += __shfl_xor(s, 8);
      if (lr == 0) atomicAdd(&lsum[b * 2048 + q0 + row_l + v], s);
    }
  }
}

// ---------------------------------------------------------------- O = P @ z, divide by lsum
// A = packed P tiles (q x keys), B = zT[b][n][keys] (NT), causal k-range 0..mt
__global__ __launch_bounds__(256, 3) void pv_out(const unsigned short* __restrict__ P,
                                                 const unsigned short* __restrict__ zT,
                                                 const float* __restrict__ lsum,
                                                 float* __restrict__ out) {
  __shared__ bf16x8 a_lds[512];
  __shared__ bf16x8 b_lds[512];
  const int tid = threadIdx.x, wid = tid >> 6, lane = tid & 63;
  const int wr = wid >> 1, wc = wid & 1, lr = lane & 15, lq = lane >> 4;
  const int g = blockIdx.x, b = g & 7, gg = g >> 3;
  const int mt = 15 - (gg >> 3), ntile = gg & 7;   // long k-loops dispatched first
  const int q0 = mt * 128, n0 = ntile * 128;
  const unsigned short* Pb = P + (size_t)b * 136 * 16384;
  const unsigned short* zTb = zT + (size_t)b * 1024 * 2048;
  const int tri = mt * (mt + 1) / 2;

  floatx4 acc[4][4] = {};
  const int arow0 = (2 * wid + 0) * 16 + lr;
  const int arow1 = (2 * wid + 1) * 16 + lr;
  const unsigned short* gb0 = zTb + (n0 + (2 * wid + 0) * 16 + lr) * 2048 + lq * 8;
  const unsigned short* gb1 = zTb + (n0 + (2 * wid + 1) * 16 + lr) * 2048 + lq * 8;
  bf16x8* la0 = &a_lds[(2 * wid + 0) * 64];
  bf16x8* la1 = &a_lds[(2 * wid + 1) * 64];
  bf16x8* lb0 = &b_lds[(2 * wid + 0) * 64];
  bf16x8* lb1 = &b_lds[(2 * wid + 1) * 64];

  for (int kt = 0; kt <= mt; ++kt) {
    const unsigned short* At = Pb + (size_t)(tri + kt) * 16384;
    const unsigned short* ga0 = At + arow0 * 128 + lq * 8;
    const unsigned short* ga1 = At + arow1 * 128 + lq * 8;
    const unsigned short* gbk0 = gb0 + kt * 128;
    const unsigned short* gbk1 = gb1 + kt * 128;
#pragma unroll
    for (int ks = 0; ks < 4; ++ks) {
      const int k0 = ks * 32;
      stage16(ga0 + k0, la0);
      stage16(ga1 + k0, la1);
      stage16(gbk0 + k0, lb0);
      stage16(gbk1 + k0, lb1);
      __syncthreads();
      bf16x8 af[4], bfr[4];
#pragma unroll
      for (int i = 0; i < 4; ++i) af[i] = a_lds[(wr * 4 + i) * 64 + lane];
#pragma unroll
      for (int j = 0; j < 4; ++j) bfr[j] = b_lds[(wc * 4 + j) * 64 + lane];
#pragma unroll
      for (int i = 0; i < 4; ++i)
#pragma unroll
        for (int j = 0; j < 4; ++j) acc[i][j] = mfma16(af[i], bfr[j], acc[i][j]);
      __syncthreads();
    }
  }

  float* outb = out + (size_t)b * 2048 * 1024;
#pragma unroll
  for (int i = 0; i < 4; ++i) {
    const int row_l = wr * 64 + i * 16 + lq * 4;
    floatx4 linv;
#pragma unroll
    for (int v = 0; v < 4; ++v) linv[v] = 1.0f / lsum[b * 2048 + q0 + row_l + v];
#pragma unroll
    for (int j = 0; j < 4; ++j) {
      const int col = n0 + wc * 64 + j * 16 + lr;
#pragma unroll
      for (int v = 0; v < 4; ++v)
        outb[(size_t)(q0 + row_l + v) * 1024 + col] = acc[i][j][v] * linv[v];
    }
  }
}

// ---------------------------------------------------------------- launcher
extern "C" void kernel_launch(void* const* d_in, const int* in_sizes, int n_in,
                              void* d_out, int out_size, void* d_ws, size_t ws_size,
                              hipStream_t stream) {
  const float* x = (const float*)d_in[0];  // [8][2048][1024]
  const float* W = (const float*)d_in[1];  // [1024][1024]
  float* out = (float*)d_out;              // [8][2048][1024]
  char* ws = (char*)d_ws;
  unsigned short* xb = (unsigned short*)ws;                          // 32 MiB bf16 x
  unsigned short* zT = (unsigned short*)(ws + 33554432ull);          // 32 MiB bf16 z^T
  unsigned short* P  = (unsigned short*)(ws + 67108864ull);          // 34 MiB packed tri P
  unsigned short* wb = P;  // alias: wb only needed by gemm_zT, P written later by qk_exp
  float* lsum = (float*)(ws + 67108864ull + 35651584ull);            // 64 KiB row sums

  cast_kernel<<<17472, 256, 0, stream>>>((const float4*)x, (const float4*)W,
                                         (ushort4*)xb, (ushort4*)wb, lsum);
  gemm_zT<<<1024, 256, 0, stream>>>(xb, wb, zT);
  qk_exp<<<1088, 256, 0, stream>>>(xb, P, lsum);
  pv_out<<<1024, 256, 0, stream>>>(P, zT, lsum, out);
}

// Round 3
// 347.119 us; speedup vs baseline: 1.6922x; 1.0245x over previous
//
#include <hip/hip_runtime.h>

typedef __attribute__((ext_vector_type(8))) __bf16 bf16x8;
typedef __attribute__((ext_vector_type(4))) float floatx4;

static __device__ __forceinline__ floatx4 mfma16(bf16x8 a, bf16x8 b, floatx4 c) {
  return __builtin_amdgcn_mfma_f32_16x16x32_bf16(a, b, c, 0, 0, 0);
}

static __device__ __forceinline__ unsigned short f2b_bits(float f) {
  __bf16 h = (__bf16)f;
  return __builtin_bit_cast(unsigned short, h);
}

// async global -> LDS, 16B per lane. LDS dest is wave-uniform base + lane*16.
static __device__ __forceinline__ void stage16(const void* g, void* l) {
  __builtin_amdgcn_global_load_lds(
      (__attribute__((address_space(1))) void*)(unsigned long long)g,
      (__attribute__((address_space(3))) void*)(unsigned int)(unsigned long long)l,
      16, 0, 0);
}

// ---------------------------------------------------------------- cast + zero lsum
__global__ void cast_kernel(const float4* __restrict__ x, const float4* __restrict__ w,
                            ushort4* __restrict__ xb, ushort4* __restrict__ wb,
                            float* __restrict__ lsum) {
  int i = blockIdx.x * 256 + threadIdx.x;
  if (i < 4194304) {
    float4 v = x[i];
    ushort4 o;
    o.x = f2b_bits(v.x); o.y = f2b_bits(v.y); o.z = f2b_bits(v.z); o.w = f2b_bits(v.w);
    xb[i] = o;
  } else if (i < 4456448) {
    int j = i - 4194304;
    float4 v = w[j];
    ushort4 o;
    o.x = f2b_bits(v.x); o.y = f2b_bits(v.y); o.z = f2b_bits(v.z); o.w = f2b_bits(v.w);
    wb[j] = o;
  } else {
    int j = i - 4456448;
    if (j < 16384) lsum[j] = 0.0f;
  }
}

// ---------------------------------------------------------------- z^T = (x @ W^T)^T
// dbuf ping-pong: 1 barrier/iter, next-tile stage16 issued right after barrier.
__global__ __launch_bounds__(256, 4) void gemm_zT(const unsigned short* __restrict__ xb,
                                                  const unsigned short* __restrict__ wb,
                                                  unsigned short* __restrict__ zT) {
  __shared__ bf16x8 a_lds[2][512];
  __shared__ bf16x8 b_lds[2][512];
  const int tid = threadIdx.x, wid = tid >> 6, lane = tid & 63;
  const int wr = wid >> 1, wc = wid & 1, lr = lane & 15, lq = lane >> 4;
  const int g = blockIdx.x;
  const int xt = g & 127, yt = g >> 7;
  const int m0 = xt * 128, n0 = yt * 128;

  floatx4 acc[4][4] = {};
  const unsigned short* ga0 = xb + (m0 + (2 * wid + 0) * 16 + lr) * 1024 + lq * 8;
  const unsigned short* ga1 = xb + (m0 + (2 * wid + 1) * 16 + lr) * 1024 + lq * 8;
  const unsigned short* gb0 = wb + (n0 + (2 * wid + 0) * 16 + lr) * 1024 + lq * 8;
  const unsigned short* gb1 = wb + (n0 + (2 * wid + 1) * 16 + lr) * 1024 + lq * 8;

  stage16(ga0, &a_lds[0][(2 * wid + 0) * 64]);
  stage16(ga1, &a_lds[0][(2 * wid + 1) * 64]);
  stage16(gb0, &b_lds[0][(2 * wid + 0) * 64]);
  stage16(gb1, &b_lds[0][(2 * wid + 1) * 64]);

  for (int it = 0; it < 32; ++it) {
    const int cur = it & 1;
    __syncthreads();  // buf[cur] staged; buf[cur^1] reads (prev iter) complete
    if (it + 1 < 32) {
      const int nb = cur ^ 1, k = (it + 1) * 32;
      stage16(ga0 + k, &a_lds[nb][(2 * wid + 0) * 64]);
      stage16(ga1 + k, &a_lds[nb][(2 * wid + 1) * 64]);
      stage16(gb0 + k, &b_lds[nb][(2 * wid + 0) * 64]);
      stage16(gb1 + k, &b_lds[nb][(2 * wid + 1) * 64]);
    }
    bf16x8 af[4], bfr[4];
#pragma unroll
    for (int i = 0; i < 4; ++i) af[i] = a_lds[cur][(wr * 4 + i) * 64 + lane];
#pragma unroll
    for (int j = 0; j < 4; ++j) bfr[j] = b_lds[cur][(wc * 4 + j) * 64 + lane];
#pragma unroll
    for (int i = 0; i < 4; ++i)
#pragma unroll
      for (int j = 0; j < 4; ++j) acc[i][j] = mfma16(af[i], bfr[j], acc[i][j]);
  }

  const int bb = m0 >> 11, sb = m0 & 2047;
#pragma unroll
  for (int i = 0; i < 4; ++i) {
    const int srow = sb + wr * 64 + i * 16 + lq * 4;
#pragma unroll
    for (int j = 0; j < 4; ++j) {
      const int n = n0 + wc * 64 + j * 16 + lr;
      ushort4 o;
      o.x = f2b_bits(acc[i][j][0]); o.y = f2b_bits(acc[i][j][1]);
      o.z = f2b_bits(acc[i][j][2]); o.w = f2b_bits(acc[i][j][3]);
      *(ushort4*)(zT + (((size_t)(bb << 10) | n) * 2048 + srow)) = o;
    }
  }
}

// ---------------------------------------------------------------- QK^T + exp epilogue
__global__ __launch_bounds__(256, 4) void qk_exp(const unsigned short* __restrict__ xb,
                                                 unsigned short* __restrict__ P,
                                                 float* __restrict__ lsum) {
  __shared__ bf16x8 a_lds[2][512];
  __shared__ bf16x8 b_lds[2][512];
  const int tid = threadIdx.x, wid = tid >> 6, lane = tid & 63;
  const int wr = wid >> 1, wc = wid & 1, lr = lane & 15, lq = lane >> 4;
  const int t = blockIdx.x, b = t & 7, idx = t >> 3;
  int mt = (int)((sqrtf(8.0f * idx + 1.0f) - 1.0f) * 0.5f);
  while ((mt + 1) * (mt + 2) / 2 <= idx) ++mt;
  while (mt * (mt + 1) / 2 > idx) --mt;
  const int nt = idx - mt * (mt + 1) / 2;
  const unsigned short* xbb = xb + (size_t)b * (2048 * 1024);
  const int q0 = mt * 128, k0t = nt * 128;

  floatx4 acc[4][4] = {};
  const unsigned short* ga0 = xbb + (q0 + (2 * wid + 0) * 16 + lr) * 1024 + lq * 8;
  const unsigned short* ga1 = xbb + (q0 + (2 * wid + 1) * 16 + lr) * 1024 + lq * 8;
  const unsigned short* gb0 = xbb + (k0t + (2 * wid + 0) * 16 + lr) * 1024 + lq * 8;
  const unsigned short* gb1 = xbb + (k0t + (2 * wid + 1) * 16 + lr) * 1024 + lq * 8;

  stage16(ga0, &a_lds[0][(2 * wid + 0) * 64]);
  stage16(ga1, &a_lds[0][(2 * wid + 1) * 64]);
  stage16(gb0, &b_lds[0][(2 * wid + 0) * 64]);
  stage16(gb1, &b_lds[0][(2 * wid + 1) * 64]);

  for (int it = 0; it < 32; ++it) {
    const int cur = it & 1;
    __syncthreads();
    if (it + 1 < 32) {
      const int nb = cur ^ 1, k = (it + 1) * 32;
      stage16(ga0 + k, &a_lds[nb][(2 * wid + 0) * 64]);
      stage16(ga1 + k, &a_lds[nb][(2 * wid + 1) * 64]);
      stage16(gb0 + k, &b_lds[nb][(2 * wid + 0) * 64]);
      stage16(gb1 + k, &b_lds[nb][(2 * wid + 1) * 64]);
    }
    bf16x8 af[4], bfr[4];
#pragma unroll
    for (int i = 0; i < 4; ++i) af[i] = a_lds[cur][(wr * 4 + i) * 64 + lane];
#pragma unroll
    for (int j = 0; j < 4; ++j) bfr[j] = b_lds[cur][(wc * 4 + j) * 64 + lane];
#pragma unroll
    for (int i = 0; i < 4; ++i)
#pragma unroll
      for (int j = 0; j < 4; ++j) acc[i][j] = mfma16(af[i], bfr[j], acc[i][j]);
  }

  unsigned short* Pt = P + ((size_t)b * 136 + (size_t)(mt * (mt + 1) / 2 + nt)) * 16384;
  const bool diag = (mt == nt);
#pragma unroll
  for (int i = 0; i < 4; ++i) {
    const int row_l = wr * 64 + i * 16 + lq * 4;
    floatx4 rs = {0.0f, 0.0f, 0.0f, 0.0f};
#pragma unroll
    for (int j = 0; j < 4; ++j) {
      const int col_l = wc * 64 + j * 16 + lr;
#pragma unroll
      for (int v = 0; v < 4; ++v) {
        float p = __expf(acc[i][j][v] * 0.03125f - 44.0f);
        if (diag && col_l > row_l + v) p = 0.0f;
        Pt[(row_l + v) * 128 + col_l] = f2b_bits(p);
        rs[v] += p;
      }
    }
#pragma unroll
    for (int v = 0; v < 4; ++v) {
      float s = rs[v];
      s += __shfl_xor(s, 1);
      s += __shfl_xor(s, 2);
      s += __shfl_xor(s, 4);
      s += __shfl_xor(s, 8);
      if (lr == 0) atomicAdd(&lsum[b * 2048 + q0 + row_l + v], s);
    }
  }
}

// ---------------------------------------------------------------- O = P @ z, divide by lsum
__global__ __launch_bounds__(256, 4) void pv_out(const unsigned short* __restrict__ P,
                                                 const unsigned short* __restrict__ zT,
                                                 const float* __restrict__ lsum,
                                                 float* __restrict__ out) {
  __shared__ bf16x8 a_lds[2][512];
  __shared__ bf16x8 b_lds[2][512];
  const int tid = threadIdx.x, wid = tid >> 6, lane = tid & 63;
  const int wr = wid >> 1, wc = wid & 1, lr = lane & 15, lq = lane >> 4;
  const int g = blockIdx.x, b = g & 7, gg = g >> 3;
  const int mt = 15 - (gg >> 3), ntile = gg & 7;   // long k-loops dispatched first
  const int q0 = mt * 128, n0 = ntile * 128;
  const unsigned short* Pb = P + (size_t)b * 136 * 16384;
  const unsigned short* zTb = zT + (size_t)b * 1024 * 2048;
  const int tri = mt * (mt + 1) / 2;
  const int ktot = (mt + 1) * 4;  // number of BK=32 steps

  floatx4 acc[4][4] = {};
  // A (P tiles): addr = base + (kk>>2)*16384 + (kk&3)*32
  const unsigned short* gaA0 = Pb + (size_t)tri * 16384 + ((2 * wid + 0) * 16 + lr) * 128 + lq * 8;
  const unsigned short* gaA1 = Pb + (size_t)tri * 16384 + ((2 * wid + 1) * 16 + lr) * 128 + lq * 8;
  // B (zT): keys contiguous, addr = base + kk*32
  const unsigned short* gbB0 = zTb + (n0 + (2 * wid + 0) * 16 + lr) * 2048 + lq * 8;
  const unsigned short* gbB1 = zTb + (n0 + (2 * wid + 1) * 16 + lr) * 2048 + lq * 8;

  stage16(gaA0, &a_lds[0][(2 * wid + 0) * 64]);
  stage16(gaA1, &a_lds[0][(2 * wid + 1) * 64]);
  stage16(gbB0, &b_lds[0][(2 * wid + 0) * 64]);
  stage16(gbB1, &b_lds[0][(2 * wid + 1) * 64]);

  for (int kk = 0; kk < ktot; ++kk) {
    const int cur = kk & 1;
    __syncthreads();
    if (kk + 1 < ktot) {
      const int nb = cur ^ 1, nk = kk + 1;
      const int aoff = (nk >> 2) * 16384 + (nk & 3) * 32;
      stage16(gaA0 + aoff, &a_lds[nb][(2 * wid + 0) * 64]);
      stage16(gaA1 + aoff, &a_lds[nb][(2 * wid + 1) * 64]);
      stage16(gbB0 + nk * 32, &b_lds[nb][(2 * wid + 0) * 64]);
      stage16(gbB1 + nk * 32, &b_lds[nb][(2 * wid + 1) * 64]);
    }
    bf16x8 af[4], bfr[4];
#pragma unroll
    for (int i = 0; i < 4; ++i) af[i] = a_lds[cur][(wr * 4 + i) * 64 + lane];
#pragma unroll
    for (int j = 0; j < 4; ++j) bfr[j] = b_lds[cur][(wc * 4 + j) * 64 + lane];
#pragma unroll
    for (int i = 0; i < 4; ++i)
#pragma unroll
      for (int j = 0; j < 4; ++j) acc[i][j] = mfma16(af[i], bfr[j], acc[i][j]);
  }

  float* outb = out + (size_t)b * 2048 * 1024;
#pragma unroll
  for (int i = 0; i < 4; ++i) {
    const int row_l = wr * 64 + i * 16 + lq * 4;
    floatx4 linv;
#pragma unroll
    for (int v = 0; v < 4; ++v) linv[v] = 1.0f / lsum[b * 2048 + q0 + row_l + v];
#pragma unroll
    for (int j = 0; j < 4; ++j) {
      const int col = n0 + wc * 64 + j * 16 + lr;
#pragma unroll
      for (int v = 0; v < 4; ++v)
        outb[(size_t)(q0 + row_l + v) * 1024 + col] = acc[i][j][v] * linv[v];
    }
  }
}

// ---------------------------------------------------------------- launcher
extern "C" void kernel_launch(void* const* d_in, const int* in_sizes, int n_in,
                              void* d_out, int out_size, void* d_ws, size_t ws_size,
                              hipStream_t stream) {
  const float* x = (const float*)d_in[0];  // [8][2048][1024]
  const float* W = (const float*)d_in[1];  // [1024][1024]
  float* out = (float*)d_out;              // [8][2048][1024]
  char* ws = (char*)d_ws;
  unsigned short* xb = (unsigned short*)ws;                          // 32 MiB bf16 x
  unsigned short* zT = (unsigned short*)(ws + 33554432ull);          // 32 MiB bf16 z^T
  unsigned short* P  = (unsigned short*)(ws + 67108864ull);          // 34 MiB packed tri P
  unsigned short* wb = P;  // alias: wb consumed by gemm_zT before P is written
  float* lsum = (float*)(ws + 67108864ull + 35651584ull);            // 64 KiB row sums

  cast_kernel<<<17472, 256, 0, stream>>>((const float4*)x, (const float4*)W,
                                         (ushort4*)xb, (ushort4*)wb, lsum);
  gemm_zT<<<1024, 256, 0, stream>>>(xb, wb, zT);
  qk_exp<<<1088, 256, 0, stream>>>(xb, P, lsum);
  pv_out<<<1024, 256, 0, stream>>>(P, zT, lsum, out);
}